// Round 12
// baseline (138.410 us; speedup 1.0000x reference)
//
#include <hip/hip_runtime.h>

// N=4, C=32(n_feats), H=W=300, P=5 fixed by setup_inputs.
#define HW        90000
#define OUT_HALF  11520000
#define CPLANE    11520000ull            // shorts per conv plane (4*90000*32)
#define WPACK_OFF  46080000ull           // bytes: 2 planes * 23.04 MB
#define ZOFF       46227456ull           // 64B zero block (after 147456B wpack)
#define WS_NEED    (46227456ull + 64ull)

typedef short short8 __attribute__((ext_vector_type(8)));
typedef float f32x4  __attribute__((ext_vector_type(4)));
typedef unsigned int u32;

__device__ inline short f2bf(float f) {
    unsigned u = __builtin_bit_cast(unsigned, f);
    u += 0x7fff + ((u >> 16) & 1);            // RNE
    return (short)(u >> 16);
}
__device__ inline float bf2f(short s) {
    unsigned u = ((unsigned)(unsigned short)s) << 16;
    return __builtin_bit_cast(float, u);
}
// async global->LDS, 16B per lane, LDS dest = wave-uniform base + lane*16
__device__ inline void gload16(char* ldst, const short* gsrc) {
    __builtin_amdgcn_global_load_lds(
        (const __attribute__((address_space(1))) u32*)gsrc,
        (__attribute__((address_space(3))) u32*)ldst, 16, 0, 0);
}

// ---- weight pack for mfma_f32_16x16x32_bf16 A-operand, gamma folded in ----
// A-frag: lane l holds A[row=l&15][k = 8*(l>>4)+e], e=0..7 contiguous.
// layout: [conv][kb=4][t=9][h=2][lane=64][e=8], co = h*16+(l&15), cin = kb*32+8*(l>>4)+e
__global__ __launch_bounds__(256)
void pack_weights(const float* __restrict__ wR, const float* __restrict__ wH,
                  const float* __restrict__ rg, const float* __restrict__ hg,
                  short* __restrict__ wpack) {
    int id = blockIdx.x * 256 + threadIdx.x;   // 2*4*9*2*64*8 = 73728
    if (id >= 73728) return;
    int e    = id & 7;
    int lane = (id >> 3) & 63;
    int h    = (id >> 9) & 1;
    int t    = (id >> 10) % 9;
    int kb   = ((id >> 10) / 9) & 3;
    int conv = id / 36864;
    int co   = h * 16 + (lane & 15);
    int cin  = kb * 32 + (lane >> 4) * 8 + e;
    const float* w = conv ? wH : wR;
    const float* g = conv ? hg : rg;
    wpack[id] = f2bf(w[(co * 128 + cin) * 9 + t] * g[cin >> 5]);
}

// ---- NCHW f32 -> per-conv NHWC bf16 planes: cmb[conv][n][y][x][32ch] ----
__global__ __launch_bounds__(256)
void nchw2nhwc(const float* __restrict__ xrgb, const float* __restrict__ yhsi,
               short* __restrict__ cmb) {
    int wave = threadIdx.x >> 6, lane = threadIdx.x & 63;
    if (lane >= 60) return;
    int y = blockIdx.y * 4 + wave;
    int x = blockIdx.x * 60 + lane;
    int n = blockIdx.z;
    const float* xb = xrgb + n * 32 * HW + y * 300 + x;
    const float* yb = yhsi + n * 32 * HW + y * 300 + x;
    size_t pxo = ((size_t)n * HW + y * 300 + x) * 32;
    short* d0 = cmb + pxo;
    short* d1 = cmb + CPLANE + pxo;
    #pragma unroll
    for (int q = 0; q < 4; ++q) {
        short8 v0, v1;
        #pragma unroll
        for (int e = 0; e < 8; ++e) {
            int c = q * 8 + e;
            v0[e] = f2bf((c < 16) ? xb[(16 + c) * HW] : yb[c * HW]);
            v1[e] = f2bf((c < 16) ? xb[c * HW] : yb[(c - 16) * HW]);
        }
        *(short8*)(d0 + q * 8) = v0;
        *(short8*)(d1 + q * 8) = v1;
    }
}

// ---- conv: 16x16 tile, halo 18x18=324px (pad 336), dbuf 43KB, gload_lds staging ----
__global__ __launch_bounds__(256, 3)
void conv_mfma(const short* __restrict__ cmb_all, const short* __restrict__ wpack,
               const int* __restrict__ corr, const short* __restrict__ zbuf,
               const float* __restrict__ bR, const float* __restrict__ bH,
               float* __restrict__ out) {
    __shared__ alignas(16) char lds[2][21504];   // 2 x 336px x 64B
    int tile = blockIdx.x;
    int n = blockIdx.y;
    int conv = blockIdx.z;
    int ty = tile / 19, tx = tile - ty * 19;
    int y0 = ty * 16, x0 = tx * 16;
    int tid = threadIdx.x;
    int wave = tid >> 6, lane = tid & 63;

    const short* cmb = cmb_all + conv * CPLANE + (size_t)n * HW * 32;
    const short* wp  = wpack + conv * 36864;

    // ---- per-lane staging precompute: instr j = wave + ji*4 covers physical
    // pixels 16j..16j+15; lane l supplies physical 16B slot off = j*1024+l*16.
    // Inverse-swizzle to logical (pixel, chunk), then that pixel's 4 gather offs.
    int  psoff[6][4];
    int  gaddr_c[6];        // c_log*8 (shorts)
    bool pvalid[6];
    #pragma unroll
    for (int ji = 0; ji < 6; ++ji) {
        pvalid[ji] = false;
        gaddr_c[ji] = 0;
        psoff[ji][0] = psoff[ji][1] = psoff[ji][2] = psoff[ji][3] = 0;
        int j = wave + ji * 4;
        if (j < 21) {
            int off = j * 1024 + lane * 16;
            int pxp = off >> 6;
            int pxl = pxp ^ ((pxp >> 2) & 1);              // inverse of write swizzle
            int cl  = ((off >> 4) & 3) ^ (pxl & 3);
            gaddr_c[ji] = cl * 8;
            if (pxl < 324) {
                int hr = pxl / 18, hc = pxl - hr * 18;
                int gy = y0 + hr - 1, gx = x0 + hc - 1;
                if (gy >= 0 && gy < 300 && gx >= 0 && gx < 300) {
                    pvalid[ji] = true;
                    int pr = gy / 5, pc = gx / 5;
                    int sj = pr * 60 + pc;
                    int sintra = (gy - pr * 5) * 300 + (gx - pc * 5);
                    const int* scr = corr + (n * 3600 + sj) * 4;
                    int j1 = scr[1], j2 = scr[2], j3 = scr[3];
                    psoff[ji][0] = (sj / 60) * 1500 + (sj % 60) * 5 + sintra;
                    psoff[ji][1] = (j1 / 60) * 1500 + (j1 % 60) * 5 + sintra;
                    psoff[ji][2] = (j2 / 60) * 1500 + (j2 % 60) * 5 + sintra;
                    psoff[ji][3] = (j3 / 60) * 1500 + (j3 % 60) * 5 + sintra;
                }
            }
        }
    }

    #define STAGE(buf, k)                                                        \
        do {                                                                     \
            _Pragma("unroll")                                                    \
            for (int ji = 0; ji < 6; ++ji) {                                     \
                int j = wave + ji * 4;                                           \
                if (j < 21) {                                                    \
                    const short* g = pvalid[ji]                                  \
                        ? (cmb + (size_t)psoff[ji][k] * 32 + gaddr_c[ji])        \
                        : (zbuf + gaddr_c[ji]);                                  \
                    gload16(&lds[buf][j * 1024], g);                             \
                }                                                                \
            }                                                                    \
        } while (0)

    STAGE(0, 0);
    __syncthreads();

    int l15 = lane & 15, lh = lane >> 4;
    int wr = wave * 4;                       // wave's first output row within tile

    f32x4 acc[4][2];
    #pragma unroll
    for (int g = 0; g < 4; ++g)
        #pragma unroll
        for (int h = 0; h < 2; ++h)
            acc[g][h] = (f32x4){0.f, 0.f, 0.f, 0.f};

    #pragma unroll
    for (int kb = 0; kb < 4; ++kb) {
        if (kb == 0) STAGE(1, 1);
        if (kb == 1) STAGE(0, 2);
        if (kb == 2) STAGE(1, 3);
        const char* base = lds[kb & 1];
        #pragma unroll
        for (int dxi = 0; dxi < 3; ++dxi) {
            short8 a[3][2];
            #pragma unroll
            for (int dyi = 0; dyi < 3; ++dyi) {
                int t = dyi * 3 + dxi;
                a[dyi][0] = *(const short8*)(wp + (((kb * 9 + t) * 2 + 0) * 64 + lane) * 8);
                a[dyi][1] = *(const short8*)(wp + (((kb * 9 + t) * 2 + 1) * 64 + lane) * 8);
            }
            short8 b[6];
            #pragma unroll
            for (int rr = 0; rr < 6; ++rr) {
                int hp = (wr + rr) * 18 + (l15 + dxi);
                b[rr] = *(const short8*)(base + ((hp * 64 + lh * 16) ^ ((hp & 7) << 4)));
            }
            #pragma unroll
            for (int g = 0; g < 4; ++g) {
                #pragma unroll
                for (int dyi = 0; dyi < 3; ++dyi) {
                    acc[g][0] = __builtin_amdgcn_mfma_f32_16x16x32_bf16(a[dyi][0], b[g + dyi], acc[g][0], 0, 0, 0);
                    acc[g][1] = __builtin_amdgcn_mfma_f32_16x16x32_bf16(a[dyi][1], b[g + dyi], acc[g][1], 0, 0, 0);
                }
            }
        }
        if (kb < 3) __syncthreads();
    }

    // epilogue: residual+bias from cmb (dense 64B per lane, bf16)
    const float* bias = conv ? bH : bR;
    #pragma unroll
    for (int g = 0; g < 4; ++g) {
        int gy = y0 + wr + g;
        int gx = x0 + l15;
        if (gy < 300 && gx < 300) {
            int pixo = gy * 300 + gx;
            const short* resp = cmb + (size_t)pixo * 32;
            short8 r0 = *(const short8*)(resp);
            short8 r1 = *(const short8*)(resp + 8);
            short8 r2 = *(const short8*)(resp + 16);
            short8 r3 = *(const short8*)(resp + 24);
            #pragma unroll
            for (int h = 0; h < 2; ++h) {
                #pragma unroll
                for (int reg = 0; reg < 4; ++reg) {
                    int co = h * 16 + lh * 4 + reg;
                    int q = co >> 3, e = co & 7;
                    float res = bf2f(q == 0 ? r0[e] : q == 1 ? r1[e] : q == 2 ? r2[e] : r3[e]);
                    out[conv * OUT_HALF + (n * 32 + co) * HW + pixo] = acc[g][h][reg] + bias[co] + res;
                }
            }
        }
    }
    #undef STAGE
}

// ---- fallback (round-1 kernel) if ws too small ----
__global__ __launch_bounds__(256)
void fused_gather_conv(const float* __restrict__ xrgb, const float* __restrict__ yhsi,
                       const int* __restrict__ corr, const float* __restrict__ rgb_gamma,
                       const float* __restrict__ hsi_gamma, const float* __restrict__ wR,
                       const float* __restrict__ bR, const float* __restrict__ wH,
                       const float* __restrict__ bH, float* __restrict__ out) {
    int tid = blockIdx.x * blockDim.x + threadIdx.x;
    if (tid >= 4 * HW) return;
    int n = tid / HW, pix = tid - n * HW;
    int y = pix / 300, x = pix - y * 300;
    const int* idx = corr + n * (3600 * 4);
    const float* xb = xrgb + n * (32 * HW);
    const float* yb = yhsi + n * (32 * HW);
    float accR[32], accH[32];
    #pragma unroll
    for (int i = 0; i < 32; ++i) { accR[i] = 0.f; accH[i] = 0.f; }
    for (int k = 0; k < 4; ++k) {
        float gr = rgb_gamma[k], gh = hsi_gamma[k];
        int off[9];
        #pragma unroll
        for (int t = 0; t < 9; ++t) {
            int dy = t / 3 - 1, dx = t % 3 - 1;
            int yy = y + dy, xx = x + dx;
            int o = -1;
            if (yy >= 0 && yy < 300 && xx >= 0 && xx < 300) {
                int pr = yy / 5, pc = xx / 5;
                int j = pr * 60 + pc;
                int jp = (k == 0) ? j : idx[j * 4 + k];
                o = ((jp / 60) * 5 + (yy - pr * 5)) * 300 + (jp % 60) * 5 + (xx - pc * 5);
            }
            off[t] = o;
        }
        for (int c = 0; c < 32; ++c) {
            const float* srcR = (c < 16) ? (xb + (16 + c) * HW) : (yb + c * HW);
            const float* srcH = (c < 16) ? (xb + c * HW) : (yb + (c - 16) * HW);
            float vr[9], vh[9];
            #pragma unroll
            for (int t = 0; t < 9; ++t) {
                bool vld = off[t] >= 0;
                vr[t] = vld ? gr * srcR[off[t]] : 0.f;
                vh[t] = vld ? gh * srcH[off[t]] : 0.f;
            }
            const float* wRp = wR + (k * 32 + c) * 9;
            const float* wHp = wH + (k * 32 + c) * 9;
            #pragma unroll
            for (int t = 0; t < 9; ++t)
                #pragma unroll
                for (int co = 0; co < 32; ++co) {
                    accR[co] = fmaf(vr[t], wRp[co * 1152 + t], accR[co]);
                    accH[co] = fmaf(vh[t], wHp[co * 1152 + t], accH[co]);
                }
        }
    }
    #pragma unroll
    for (int co = 0; co < 32; ++co) {
        float resR = (co < 16) ? xb[(16 + co) * HW + pix] : yb[co * HW + pix];
        float resH = (co < 16) ? xb[co * HW + pix] : yb[(co - 16) * HW + pix];
        out[(n * 32 + co) * HW + pix]            = accR[co] + bR[co] + resR;
        out[OUT_HALF + (n * 32 + co) * HW + pix] = accH[co] + bH[co] + resH;
    }
}

extern "C" void kernel_launch(void* const* d_in, const int* in_sizes, int n_in,
                              void* d_out, int out_size, void* d_ws, size_t ws_size,
                              hipStream_t stream) {
    const float* xrgb = (const float*)d_in[0];
    const float* yhsi = (const float*)d_in[1];
    const int*   corr = (const int*)d_in[2];
    const float* rg   = (const float*)d_in[3];
    const float* hg   = (const float*)d_in[4];
    const float* wR   = (const float*)d_in[5];
    const float* bR   = (const float*)d_in[6];
    const float* wH   = (const float*)d_in[7];
    const float* bH   = (const float*)d_in[8];
    float* out = (float*)d_out;

    if (ws_size >= WS_NEED) {
        short* cmb   = (short*)d_ws;
        short* wpack = (short*)((char*)d_ws + WPACK_OFF);
        short* zbuf  = (short*)((char*)d_ws + ZOFF);
        hipMemsetAsync((char*)d_ws + ZOFF, 0, 64, stream);
        hipLaunchKernelGGL(pack_weights, dim3(288), dim3(256), 0, stream, wR, wH, rg, hg, wpack);
        hipLaunchKernelGGL(nchw2nhwc, dim3(5, 75, 4), dim3(256), 0, stream, xrgb, yhsi, cmb);
        hipLaunchKernelGGL(conv_mfma, dim3(361, 4, 2), dim3(256), 0, stream,
                           cmb, wpack, corr, zbuf, bR, bH, out);
    } else {
        int total = 4 * HW;
        hipLaunchKernelGGL(fused_gather_conv, dim3((total + 255) / 256), dim3(256), 0, stream,
                           xrgb, yhsi, corr, rg, hg, wR, bR, wH, bH, out);
    }
}

// Round 13
// 129.675 us; speedup vs baseline: 1.0674x; 1.0674x over previous
//
#include <hip/hip_runtime.h>

// N=4, C=32(n_feats), H=W=300, P=5 fixed by setup_inputs.
#define HW        90000
#define OUT_HALF  11520000
#define CPLANE    11520000ull            // shorts per conv plane (4*90000*32)
#define WPACK_OFF  46080000ull           // bytes: 2 planes * 23.04 MB
#define ZOFF       46227456              // 64B zero block (after 147456B wpack)
#define WS_NEED    (46227456ull + 64ull)

typedef short short4v __attribute__((ext_vector_type(4)));
typedef short short8 __attribute__((ext_vector_type(8)));
typedef float f32x4  __attribute__((ext_vector_type(4)));
typedef unsigned int u32;

__device__ inline short f2bf(float f) {
    unsigned u = __builtin_bit_cast(unsigned, f);
    u += 0x7fff + ((u >> 16) & 1);            // RNE
    return (short)(u >> 16);
}
__device__ inline float bf2f(short s) {
    unsigned u = ((unsigned)(unsigned short)s) << 16;
    return __builtin_bit_cast(float, u);
}
// async global->LDS, 16B per lane, LDS dest = wave-uniform base + lane*16
__device__ inline void gload16(char* ldst, const char* gsrc) {
    __builtin_amdgcn_global_load_lds(
        (const __attribute__((address_space(1))) u32*)gsrc,
        (__attribute__((address_space(3))) u32*)ldst, 16, 0, 0);
}

// ---- weight pack for mfma_f32_16x16x32_bf16 A-operand, gamma folded in ----
// A-frag: lane l holds A[row=l&15][k = 8*(l>>4)+e], e=0..7 contiguous.
// layout: [conv][kb=4][t=9][h=2][lane=64][e=8], co = h*16+(l&15), cin = kb*32+8*(l>>4)+e
__global__ __launch_bounds__(256)
void pack_weights(const float* __restrict__ wR, const float* __restrict__ wH,
                  const float* __restrict__ rg, const float* __restrict__ hg,
                  short* __restrict__ wpack) {
    int id = blockIdx.x * 256 + threadIdx.x;   // 2*4*9*2*64*8 = 73728
    if (id >= 73728) return;
    int e    = id & 7;
    int lane = (id >> 3) & 63;
    int h    = (id >> 9) & 1;
    int t    = (id >> 10) % 9;
    int kb   = ((id >> 10) / 9) & 3;
    int conv = id / 36864;
    int co   = h * 16 + (lane & 15);
    int cin  = kb * 32 + (lane >> 4) * 8 + e;
    const float* w = conv ? wH : wR;
    const float* g = conv ? hg : rg;
    wpack[id] = f2bf(w[(co * 128 + cin) * 9 + t] * g[cin >> 5]);
}

// ---- NCHW f32 -> per-conv NHWC bf16 planes: cmb[conv][n][y][x][32ch] ----
__global__ __launch_bounds__(256)
void nchw2nhwc(const float* __restrict__ xrgb, const float* __restrict__ yhsi,
               short* __restrict__ cmb) {
    int wave = threadIdx.x >> 6, lane = threadIdx.x & 63;
    if (lane >= 60) return;
    int y = blockIdx.y * 4 + wave;
    int x = blockIdx.x * 60 + lane;
    int n = blockIdx.z;
    const float* xb = xrgb + n * 32 * HW + y * 300 + x;
    const float* yb = yhsi + n * 32 * HW + y * 300 + x;
    size_t pxo = ((size_t)n * HW + y * 300 + x) * 32;
    short* d0 = cmb + pxo;
    short* d1 = cmb + CPLANE + pxo;
    #pragma unroll
    for (int q = 0; q < 4; ++q) {
        short8 v0, v1;
        #pragma unroll
        for (int e = 0; e < 8; ++e) {
            int c = q * 8 + e;
            v0[e] = f2bf((c < 16) ? xb[(16 + c) * HW] : yb[c * HW]);
            v1[e] = f2bf((c < 16) ? xb[c * HW] : yb[(c - 16) * HW]);
        }
        *(short8*)(d0 + q * 8) = v0;
        *(short8*)(d1 + q * 8) = v1;
    }
}

// ---- conv: 16x16 tile, halo 18x18=324px (pad 336), dbuf 43KB, gload_lds staging,
// ---- precomputed staging+B offsets, short4 residual epilogue ----
__global__ __launch_bounds__(256, 3)
void conv_mfma(const char* __restrict__ wsbase, const short* __restrict__ wpack,
               const int* __restrict__ corr,
               const float* __restrict__ bR, const float* __restrict__ bH,
               float* __restrict__ out) {
    __shared__ alignas(16) char lds[2][21504];   // 2 x 336px x 64B
    int tile = blockIdx.x;
    int n = blockIdx.y;
    int conv = blockIdx.z;
    int ty = tile / 19, tx = tile - ty * 19;
    int y0 = ty * 16, x0 = tx * 16;
    int tid = threadIdx.x;
    int wave = tid >> 6, lane = tid & 63;

    const short* cmb = (const short*)wsbase + conv * CPLANE + (size_t)n * HW * 32;
    const short* wp  = wpack + conv * 36864;
    int cmb_byte = (int)(conv * (CPLANE * 2)) + n * (HW * 64);

    // ---- staging precompute: instr j = wave + ji*4 covers physical pixels
    // 16j..16j+15; lane supplies physical slot off = j*1024 + lane*16.
    // Inverse-swizzle to logical (pixel, chunk); fold everything (incl. the
    // zero-block fallback) into one byte offset from wsbase per (ji, k).
    int soffB[6][4];
    #pragma unroll
    for (int ji = 0; ji < 6; ++ji) {
        int j = wave + ji * 4;
        #pragma unroll
        for (int k = 0; k < 4; ++k) soffB[ji][k] = ZOFF;
        if (j < 21) {
            int off = j * 1024 + lane * 16;
            int pxp = off >> 6;
            int pxl = pxp ^ ((pxp >> 2) & 1);              // inverse of write swizzle
            int cl  = ((off >> 4) & 3) ^ (pxl & 3);
            int cb  = cl * 16;                             // chunk byte
            #pragma unroll
            for (int k = 0; k < 4; ++k) soffB[ji][k] = ZOFF + cb;
            if (pxl < 324) {
                int hr = pxl / 18, hc = pxl - hr * 18;
                int gy = y0 + hr - 1, gx = x0 + hc - 1;
                if (gy >= 0 && gy < 300 && gx >= 0 && gx < 300) {
                    int pr = gy / 5, pc = gx / 5;
                    int sj = pr * 60 + pc;
                    int sintra = (gy - pr * 5) * 300 + (gx - pc * 5);
                    const int* scr = corr + (n * 3600 + sj) * 4;
                    int j1 = scr[1], j2 = scr[2], j3 = scr[3];
                    soffB[ji][0] = cmb_byte + ((sj / 60) * 1500 + (sj % 60) * 5 + sintra) * 64 + cb;
                    soffB[ji][1] = cmb_byte + ((j1 / 60) * 1500 + (j1 % 60) * 5 + sintra) * 64 + cb;
                    soffB[ji][2] = cmb_byte + ((j2 / 60) * 1500 + (j2 % 60) * 5 + sintra) * 64 + cb;
                    soffB[ji][3] = cmb_byte + ((j3 / 60) * 1500 + (j3 % 60) * 5 + sintra) * 64 + cb;
                }
            }
        }
    }

    #define STAGE(buf, k)                                                        \
        do {                                                                     \
            _Pragma("unroll")                                                    \
            for (int ji = 0; ji < 6; ++ji) {                                     \
                int j = wave + ji * 4;                                           \
                if (j < 21)                                                      \
                    gload16(&lds[buf][j * 1024], wsbase + soffB[ji][(k)]);       \
            }                                                                    \
        } while (0)

    int l15 = lane & 15, lh = lane >> 4;
    int wr = wave * 4;                       // wave's first output row within tile

    // ---- B-offset precompute (kb-invariant!): boff[dxi][rr], swizzled ----
    int boff[3][6];
    #pragma unroll
    for (int dxi = 0; dxi < 3; ++dxi)
        #pragma unroll
        for (int rr = 0; rr < 6; ++rr) {
            int hp = (wr + rr) * 18 + (l15 + dxi);
            boff[dxi][rr] = (hp * 64 + lh * 16) ^ ((hp & 7) << 4);
        }

    STAGE(0, 0);
    __syncthreads();

    f32x4 acc[4][2];
    #pragma unroll
    for (int g = 0; g < 4; ++g)
        #pragma unroll
        for (int h = 0; h < 2; ++h)
            acc[g][h] = (f32x4){0.f, 0.f, 0.f, 0.f};

    #pragma unroll
    for (int kb = 0; kb < 4; ++kb) {
        if (kb == 0) STAGE(1, 1);
        if (kb == 1) STAGE(0, 2);
        if (kb == 2) STAGE(1, 3);
        const char* base = lds[kb & 1];      // compile-time 0 / 21504 per unrolled kb
        #pragma unroll
        for (int dxi = 0; dxi < 3; ++dxi) {
            short8 a[3][2];
            #pragma unroll
            for (int dyi = 0; dyi < 3; ++dyi) {
                int t = dyi * 3 + dxi;
                a[dyi][0] = *(const short8*)(wp + (((kb * 9 + t) * 2 + 0) * 64 + lane) * 8);
                a[dyi][1] = *(const short8*)(wp + (((kb * 9 + t) * 2 + 1) * 64 + lane) * 8);
            }
            short8 b[6];
            #pragma unroll
            for (int rr = 0; rr < 6; ++rr)
                b[rr] = *(const short8*)(base + boff[dxi][rr]);
            #pragma unroll
            for (int g = 0; g < 4; ++g) {
                #pragma unroll
                for (int dyi = 0; dyi < 3; ++dyi) {
                    acc[g][0] = __builtin_amdgcn_mfma_f32_16x16x32_bf16(a[dyi][0], b[g + dyi], acc[g][0], 0, 0, 0);
                    acc[g][1] = __builtin_amdgcn_mfma_f32_16x16x32_bf16(a[dyi][1], b[g + dyi], acc[g][1], 0, 0, 0);
                }
            }
        }
        if (kb < 3) __syncthreads();
    }

    // epilogue: residual via two short4 loads (exactly the 4 co each h needs)
    const float* bias = conv ? bH : bR;
    float bia[2][4];
    #pragma unroll
    for (int h = 0; h < 2; ++h)
        #pragma unroll
        for (int reg = 0; reg < 4; ++reg)
            bia[h][reg] = bias[h * 16 + lh * 4 + reg];
    #pragma unroll
    for (int g = 0; g < 4; ++g) {
        int gy = y0 + wr + g;
        int gx = x0 + l15;
        if (gy < 300 && gx < 300) {
            int pixo = gy * 300 + gx;
            const short* resp = cmb + (size_t)pixo * 32 + lh * 4;
            #pragma unroll
            for (int h = 0; h < 2; ++h) {
                short4v r = *(const short4v*)(resp + h * 16);
                #pragma unroll
                for (int reg = 0; reg < 4; ++reg) {
                    int co = h * 16 + lh * 4 + reg;
                    out[conv * OUT_HALF + (n * 32 + co) * HW + pixo]
                        = acc[g][h][reg] + bia[h][reg] + bf2f(r[reg]);
                }
            }
        }
    }
    #undef STAGE
}

// ---- fallback (round-1 kernel) if ws too small ----
__global__ __launch_bounds__(256)
void fused_gather_conv(const float* __restrict__ xrgb, const float* __restrict__ yhsi,
                       const int* __restrict__ corr, const float* __restrict__ rgb_gamma,
                       const float* __restrict__ hsi_gamma, const float* __restrict__ wR,
                       const float* __restrict__ bR, const float* __restrict__ wH,
                       const float* __restrict__ bH, float* __restrict__ out) {
    int tid = blockIdx.x * blockDim.x + threadIdx.x;
    if (tid >= 4 * HW) return;
    int n = tid / HW, pix = tid - n * HW;
    int y = pix / 300, x = pix - y * 300;
    const int* idx = corr + n * (3600 * 4);
    const float* xb = xrgb + n * (32 * HW);
    const float* yb = yhsi + n * (32 * HW);
    float accR[32], accH[32];
    #pragma unroll
    for (int i = 0; i < 32; ++i) { accR[i] = 0.f; accH[i] = 0.f; }
    for (int k = 0; k < 4; ++k) {
        float gr = rgb_gamma[k], gh = hsi_gamma[k];
        int off[9];
        #pragma unroll
        for (int t = 0; t < 9; ++t) {
            int dy = t / 3 - 1, dx = t % 3 - 1;
            int yy = y + dy, xx = x + dx;
            int o = -1;
            if (yy >= 0 && yy < 300 && xx >= 0 && xx < 300) {
                int pr = yy / 5, pc = xx / 5;
                int j = pr * 60 + pc;
                int jp = (k == 0) ? j : idx[j * 4 + k];
                o = ((jp / 60) * 5 + (yy - pr * 5)) * 300 + (jp % 60) * 5 + (xx - pc * 5);
            }
            off[t] = o;
        }
        for (int c = 0; c < 32; ++c) {
            const float* srcR = (c < 16) ? (xb + (16 + c) * HW) : (yb + c * HW);
            const float* srcH = (c < 16) ? (xb + c * HW) : (yb + (c - 16) * HW);
            float vr[9], vh[9];
            #pragma unroll
            for (int t = 0; t < 9; ++t) {
                bool vld = off[t] >= 0;
                vr[t] = vld ? gr * srcR[off[t]] : 0.f;
                vh[t] = vld ? gh * srcH[off[t]] : 0.f;
            }
            const float* wRp = wR + (k * 32 + c) * 9;
            const float* wHp = wH + (k * 32 + c) * 9;
            #pragma unroll
            for (int t = 0; t < 9; ++t)
                #pragma unroll
                for (int co = 0; co < 32; ++co) {
                    accR[co] = fmaf(vr[t], wRp[co * 1152 + t], accR[co]);
                    accH[co] = fmaf(vh[t], wHp[co * 1152 + t], accH[co]);
                }
        }
    }
    #pragma unroll
    for (int co = 0; co < 32; ++co) {
        float resR = (co < 16) ? xb[(16 + co) * HW + pix] : yb[co * HW + pix];
        float resH = (co < 16) ? xb[co * HW + pix] : yb[(co - 16) * HW + pix];
        out[(n * 32 + co) * HW + pix]            = accR[co] + bR[co] + resR;
        out[OUT_HALF + (n * 32 + co) * HW + pix] = accH[co] + bH[co] + resH;
    }
}

extern "C" void kernel_launch(void* const* d_in, const int* in_sizes, int n_in,
                              void* d_out, int out_size, void* d_ws, size_t ws_size,
                              hipStream_t stream) {
    const float* xrgb = (const float*)d_in[0];
    const float* yhsi = (const float*)d_in[1];
    const int*   corr = (const int*)d_in[2];
    const float* rg   = (const float*)d_in[3];
    const float* hg   = (const float*)d_in[4];
    const float* wR   = (const float*)d_in[5];
    const float* bR   = (const float*)d_in[6];
    const float* wH   = (const float*)d_in[7];
    const float* bH   = (const float*)d_in[8];
    float* out = (float*)d_out;

    if (ws_size >= WS_NEED) {
        short* cmb   = (short*)d_ws;
        short* wpack = (short*)((char*)d_ws + WPACK_OFF);
        hipMemsetAsync((char*)d_ws + ZOFF, 0, 64, stream);
        hipLaunchKernelGGL(pack_weights, dim3(288), dim3(256), 0, stream, wR, wH, rg, hg, wpack);
        hipLaunchKernelGGL(nchw2nhwc, dim3(5, 75, 4), dim3(256), 0, stream, xrgb, yhsi, cmb);
        hipLaunchKernelGGL(conv_mfma, dim3(361, 4, 2), dim3(256), 0, stream,
                           (const char*)d_ws, wpack, corr, bR, bH, out);
    } else {
        int total = 4 * HW;
        hipLaunchKernelGGL(fused_gather_conv, dim3((total + 255) / 256), dim3(256), 0, stream,
                           xrgb, yhsi, corr, rg, hg, wR, bR, wH, bH, out);
    }
}

// Round 14
// 126.013 us; speedup vs baseline: 1.0984x; 1.0291x over previous
//
#include <hip/hip_runtime.h>

// N=4, C=32(n_feats), H=W=300, P=5 fixed by setup_inputs.
#define HW        90000
#define OUT_HALF  11520000
#define CPLANE    11520000ull            // shorts per conv plane (4*90000*32)
#define WPACK_OFF  46080000ull           // bytes: 2 planes * 23.04 MB
#define ZOFF       46227456              // 64B zero block (after 147456B wpack)
#define WS_NEED    (46227456ull + 64ull)

typedef short short4v __attribute__((ext_vector_type(4)));
typedef short short8 __attribute__((ext_vector_type(8)));
typedef float f32x4  __attribute__((ext_vector_type(4)));
typedef unsigned int u32;

__device__ inline short f2bf(float f) {
    unsigned u = __builtin_bit_cast(unsigned, f);
    u += 0x7fff + ((u >> 16) & 1);            // RNE
    return (short)(u >> 16);
}
__device__ inline float bf2f(short s) {
    unsigned u = ((unsigned)(unsigned short)s) << 16;
    return __builtin_bit_cast(float, u);
}
// async global->LDS, 16B per lane, LDS dest = wave-uniform base + lane*16
__device__ inline void gload16(char* ldst, const char* gsrc) {
    __builtin_amdgcn_global_load_lds(
        (const __attribute__((address_space(1))) u32*)gsrc,
        (__attribute__((address_space(3))) u32*)ldst, 16, 0, 0);
}

// ---- weight pack for mfma_f32_16x16x32_bf16 A-operand, gamma folded in ----
// A-frag: lane l holds A[row=l&15][k = 8*(l>>4)+e], e=0..7 contiguous.
// layout: [conv][kb=4][t=9][h=2][lane=64][e=8], co = h*16+(l&15), cin = kb*32+8*(l>>4)+e
__global__ __launch_bounds__(256)
void pack_weights(const float* __restrict__ wR, const float* __restrict__ wH,
                  const float* __restrict__ rg, const float* __restrict__ hg,
                  short* __restrict__ wpack) {
    int id = blockIdx.x * 256 + threadIdx.x;   // 2*4*9*2*64*8 = 73728
    if (id >= 73728) return;
    int e    = id & 7;
    int lane = (id >> 3) & 63;
    int h    = (id >> 9) & 1;
    int t    = (id >> 10) % 9;
    int kb   = ((id >> 10) / 9) & 3;
    int conv = id / 36864;
    int co   = h * 16 + (lane & 15);
    int cin  = kb * 32 + (lane >> 4) * 8 + e;
    const float* w = conv ? wH : wR;
    const float* g = conv ? hg : rg;
    wpack[id] = f2bf(w[(co * 128 + cin) * 9 + t] * g[cin >> 5]);
}

// ---- NCHW f32 -> per-conv NHWC bf16 planes: cmb[conv][n][y][x][32ch] ----
__global__ __launch_bounds__(256)
void nchw2nhwc(const float* __restrict__ xrgb, const float* __restrict__ yhsi,
               short* __restrict__ cmb) {
    int wave = threadIdx.x >> 6, lane = threadIdx.x & 63;
    if (lane >= 60) return;
    int y = blockIdx.y * 4 + wave;
    int x = blockIdx.x * 60 + lane;
    int n = blockIdx.z;
    const float* xb = xrgb + n * 32 * HW + y * 300 + x;
    const float* yb = yhsi + n * 32 * HW + y * 300 + x;
    size_t pxo = ((size_t)n * HW + y * 300 + x) * 32;
    short* d0 = cmb + pxo;
    short* d1 = cmb + CPLANE + pxo;
    #pragma unroll
    for (int q = 0; q < 4; ++q) {
        short8 v0, v1;
        #pragma unroll
        for (int e = 0; e < 8; ++e) {
            int c = q * 8 + e;
            v0[e] = f2bf((c < 16) ? xb[(16 + c) * HW] : yb[c * HW]);
            v1[e] = f2bf((c < 16) ? xb[c * HW] : yb[(c - 16) * HW]);
        }
        *(short8*)(d0 + q * 8) = v0;
        *(short8*)(d1 + q * 8) = v1;
    }
}

// ---- conv: 16x16 tile, halo 18x18=324px (pad 336), dbuf 43KB, gload_lds staging.
// ---- Issue order per kb: A-frags FIRST (oldest vmem), gathers LAST (youngest),
// ---- so MFMA A-waits resolve at vmcnt(6) without draining the gathers (T4).
__global__ __launch_bounds__(256, 3)
void conv_mfma(const char* __restrict__ wsbase, const short* __restrict__ wpack,
               const int* __restrict__ corr,
               const float* __restrict__ bR, const float* __restrict__ bH,
               float* __restrict__ out) {
    __shared__ alignas(16) char lds[2][21504];   // 2 x 336px x 64B
    int tile = blockIdx.x;
    int n = blockIdx.y;
    int conv = blockIdx.z;
    int ty = tile / 19, tx = tile - ty * 19;
    int y0 = ty * 16, x0 = tx * 16;
    int tid = threadIdx.x;
    int wave = tid >> 6, lane = tid & 63;

    const short* cmb = (const short*)wsbase + conv * CPLANE + (size_t)n * HW * 32;
    const short* wp  = wpack + conv * 36864;
    int cmb_byte = (int)(conv * (CPLANE * 2)) + n * (HW * 64);

    // ---- staging precompute: instr j = wave + ji*4 covers physical pixels
    // 16j..16j+15; lane supplies physical slot off = j*1024 + lane*16.
    // Inverse-swizzle to logical (pixel, chunk); fold zero-block fallback into
    // one byte offset from wsbase per (ji, k).
    int soffB[6][4];
    #pragma unroll
    for (int ji = 0; ji < 6; ++ji) {
        int j = wave + ji * 4;
        #pragma unroll
        for (int k = 0; k < 4; ++k) soffB[ji][k] = ZOFF;
        if (j < 21) {
            int off = j * 1024 + lane * 16;
            int pxp = off >> 6;
            int pxl = pxp ^ ((pxp >> 2) & 1);              // inverse of write swizzle
            int cl  = ((off >> 4) & 3) ^ (pxl & 3);
            int cb  = cl * 16;                             // chunk byte
            #pragma unroll
            for (int k = 0; k < 4; ++k) soffB[ji][k] = ZOFF + cb;
            if (pxl < 324) {
                int hr = pxl / 18, hc = pxl - hr * 18;
                int gy = y0 + hr - 1, gx = x0 + hc - 1;
                if (gy >= 0 && gy < 300 && gx >= 0 && gx < 300) {
                    int pr = gy / 5, pc = gx / 5;
                    int sj = pr * 60 + pc;
                    int sintra = (gy - pr * 5) * 300 + (gx - pc * 5);
                    const int* scr = corr + (n * 3600 + sj) * 4;
                    int j1 = scr[1], j2 = scr[2], j3 = scr[3];
                    soffB[ji][0] = cmb_byte + ((sj / 60) * 1500 + (sj % 60) * 5 + sintra) * 64 + cb;
                    soffB[ji][1] = cmb_byte + ((j1 / 60) * 1500 + (j1 % 60) * 5 + sintra) * 64 + cb;
                    soffB[ji][2] = cmb_byte + ((j2 / 60) * 1500 + (j2 % 60) * 5 + sintra) * 64 + cb;
                    soffB[ji][3] = cmb_byte + ((j3 / 60) * 1500 + (j3 % 60) * 5 + sintra) * 64 + cb;
                }
            }
        }
    }

    #define STAGE(buf, k)                                                        \
        do {                                                                     \
            _Pragma("unroll")                                                    \
            for (int ji = 0; ji < 6; ++ji) {                                     \
                int j = wave + ji * 4;                                           \
                if (j < 21)                                                      \
                    gload16(&lds[buf][j * 1024], wsbase + soffB[ji][(k)]);       \
            }                                                                    \
        } while (0)

    int l15 = lane & 15, lh = lane >> 4;
    int wr = wave * 4;                       // wave's first output row within tile

    // ---- B-offset precompute (kb-invariant): boff[dxi][rr], swizzled ----
    int boff[3][6];
    #pragma unroll
    for (int dxi = 0; dxi < 3; ++dxi)
        #pragma unroll
        for (int rr = 0; rr < 6; ++rr) {
            int hp = (wr + rr) * 18 + (l15 + dxi);
            boff[dxi][rr] = (hp * 64 + lh * 16) ^ ((hp & 7) << 4);
        }

    STAGE(0, 0);
    __syncthreads();

    f32x4 acc[4][2];
    #pragma unroll
    for (int g = 0; g < 4; ++g)
        #pragma unroll
        for (int h = 0; h < 2; ++h)
            acc[g][h] = (f32x4){0.f, 0.f, 0.f, 0.f};

    #pragma unroll
    for (int kb = 0; kb < 4; ++kb) {
        // (1) all 18 A-frag loads of this kb — OLDEST vmem ops of the phase
        short8 a[3][3][2];
        #pragma unroll
        for (int dxi = 0; dxi < 3; ++dxi)
            #pragma unroll
            for (int dyi = 0; dyi < 3; ++dyi) {
                int t = dyi * 3 + dxi;
                a[dxi][dyi][0] = *(const short8*)(wp + (((kb * 9 + t) * 2 + 0) * 64 + lane) * 8);
                a[dxi][dyi][1] = *(const short8*)(wp + (((kb * 9 + t) * 2 + 1) * 64 + lane) * 8);
            }
        __builtin_amdgcn_sched_barrier(0);
        // (2) gathers for the next buffer — YOUNGEST vmem, drained only at barrier
        if (kb == 0) STAGE(1, 1);
        if (kb == 1) STAGE(0, 2);
        if (kb == 2) STAGE(1, 3);
        __builtin_amdgcn_sched_barrier(0);
        // (3) compute on buffer[kb&1]
        const char* base = lds[kb & 1];      // compile-time 0 / 21504 per unrolled kb
        #pragma unroll
        for (int dxi = 0; dxi < 3; ++dxi) {
            short8 b[6];
            #pragma unroll
            for (int rr = 0; rr < 6; ++rr)
                b[rr] = *(const short8*)(base + boff[dxi][rr]);
            #pragma unroll
            for (int g = 0; g < 4; ++g) {
                #pragma unroll
                for (int dyi = 0; dyi < 3; ++dyi) {
                    acc[g][0] = __builtin_amdgcn_mfma_f32_16x16x32_bf16(a[dxi][dyi][0], b[g + dyi], acc[g][0], 0, 0, 0);
                    acc[g][1] = __builtin_amdgcn_mfma_f32_16x16x32_bf16(a[dxi][dyi][1], b[g + dyi], acc[g][1], 0, 0, 0);
                }
            }
        }
        if (kb < 3) __syncthreads();
    }

    // epilogue: residual via two short4 loads (exactly the 4 co each h needs)
    const float* bias = conv ? bH : bR;
    float bia[2][4];
    #pragma unroll
    for (int h = 0; h < 2; ++h)
        #pragma unroll
        for (int reg = 0; reg < 4; ++reg)
            bia[h][reg] = bias[h * 16 + lh * 4 + reg];
    #pragma unroll
    for (int g = 0; g < 4; ++g) {
        int gy = y0 + wr + g;
        int gx = x0 + l15;
        if (gy < 300 && gx < 300) {
            int pixo = gy * 300 + gx;
            const short* resp = cmb + (size_t)pixo * 32 + lh * 4;
            #pragma unroll
            for (int h = 0; h < 2; ++h) {
                short4v r = *(const short4v*)(resp + h * 16);
                #pragma unroll
                for (int reg = 0; reg < 4; ++reg) {
                    int co = h * 16 + lh * 4 + reg;
                    out[conv * OUT_HALF + (n * 32 + co) * HW + pixo]
                        = acc[g][h][reg] + bia[h][reg] + bf2f(r[reg]);
                }
            }
        }
    }
    #undef STAGE
}

// ---- fallback (round-1 kernel) if ws too small ----
__global__ __launch_bounds__(256)
void fused_gather_conv(const float* __restrict__ xrgb, const float* __restrict__ yhsi,
                       const int* __restrict__ corr, const float* __restrict__ rgb_gamma,
                       const float* __restrict__ hsi_gamma, const float* __restrict__ wR,
                       const float* __restrict__ bR, const float* __restrict__ wH,
                       const float* __restrict__ bH, float* __restrict__ out) {
    int tid = blockIdx.x * blockDim.x + threadIdx.x;
    if (tid >= 4 * HW) return;
    int n = tid / HW, pix = tid - n * HW;
    int y = pix / 300, x = pix - y * 300;
    const int* idx = corr + n * (3600 * 4);
    const float* xb = xrgb + n * (32 * HW);
    const float* yb = yhsi + n * (32 * HW);
    float accR[32], accH[32];
    #pragma unroll
    for (int i = 0; i < 32; ++i) { accR[i] = 0.f; accH[i] = 0.f; }
    for (int k = 0; k < 4; ++k) {
        float gr = rgb_gamma[k], gh = hsi_gamma[k];
        int off[9];
        #pragma unroll
        for (int t = 0; t < 9; ++t) {
            int dy = t / 3 - 1, dx = t % 3 - 1;
            int yy = y + dy, xx = x + dx;
            int o = -1;
            if (yy >= 0 && yy < 300 && xx >= 0 && xx < 300) {
                int pr = yy / 5, pc = xx / 5;
                int j = pr * 60 + pc;
                int jp = (k == 0) ? j : idx[j * 4 + k];
                o = ((jp / 60) * 5 + (yy - pr * 5)) * 300 + (jp % 60) * 5 + (xx - pc * 5);
            }
            off[t] = o;
        }
        for (int c = 0; c < 32; ++c) {
            const float* srcR = (c < 16) ? (xb + (16 + c) * HW) : (yb + c * HW);
            const float* srcH = (c < 16) ? (xb + c * HW) : (yb + (c - 16) * HW);
            float vr[9], vh[9];
            #pragma unroll
            for (int t = 0; t < 9; ++t) {
                bool vld = off[t] >= 0;
                vr[t] = vld ? gr * srcR[off[t]] : 0.f;
                vh[t] = vld ? gh * srcH[off[t]] : 0.f;
            }
            const float* wRp = wR + (k * 32 + c) * 9;
            const float* wHp = wH + (k * 32 + c) * 9;
            #pragma unroll
            for (int t = 0; t < 9; ++t)
                #pragma unroll
                for (int co = 0; co < 32; ++co) {
                    accR[co] = fmaf(vr[t], wRp[co * 1152 + t], accR[co]);
                    accH[co] = fmaf(vh[t], wHp[co * 1152 + t], accH[co]);
                }
        }
    }
    #pragma unroll
    for (int co = 0; co < 32; ++co) {
        float resR = (co < 16) ? xb[(16 + co) * HW + pix] : yb[co * HW + pix];
        float resH = (co < 16) ? xb[co * HW + pix] : yb[(co - 16) * HW + pix];
        out[(n * 32 + co) * HW + pix]            = accR[co] + bR[co] + resR;
        out[OUT_HALF + (n * 32 + co) * HW + pix] = accH[co] + bH[co] + resH;
    }
}

extern "C" void kernel_launch(void* const* d_in, const int* in_sizes, int n_in,
                              void* d_out, int out_size, void* d_ws, size_t ws_size,
                              hipStream_t stream) {
    const float* xrgb = (const float*)d_in[0];
    const float* yhsi = (const float*)d_in[1];
    const int*   corr = (const int*)d_in[2];
    const float* rg   = (const float*)d_in[3];
    const float* hg   = (const float*)d_in[4];
    const float* wR   = (const float*)d_in[5];
    const float* bR   = (const float*)d_in[6];
    const float* wH   = (const float*)d_in[7];
    const float* bH   = (const float*)d_in[8];
    float* out = (float*)d_out;

    if (ws_size >= WS_NEED) {
        short* cmb   = (short*)d_ws;
        short* wpack = (short*)((char*)d_ws + WPACK_OFF);
        hipMemsetAsync((char*)d_ws + ZOFF, 0, 64, stream);
        hipLaunchKernelGGL(pack_weights, dim3(288), dim3(256), 0, stream, wR, wH, rg, hg, wpack);
        hipLaunchKernelGGL(nchw2nhwc, dim3(5, 75, 4), dim3(256), 0, stream, xrgb, yhsi, cmb);
        hipLaunchKernelGGL(conv_mfma, dim3(361, 4, 2), dim3(256), 0, stream,
                           (const char*)d_ws, wpack, corr, bR, bH, out);
    } else {
        int total = 4 * HW;
        hipLaunchKernelGGL(fused_gather_conv, dim3((total + 255) / 256), dim3(256), 0, stream,
                           xrgb, yhsi, corr, rg, hg, wR, bR, wH, bH, out);
    }
}